// Round 2
// baseline (84.152 us; speedup 1.0000x reference)
//
#include <hip/hip_runtime.h>
#include <math.h>

// Problem constants (from reference)
#define N_PRED 1000
#define M_BOX  2000
#define K_PASS 10
#define C_CLS  80
#define IOU_THR 0.5f
#define EPS_IOU 1e-7f

#define G_PRED 10                      // preds per block, one per wave
#define BLK_T  (G_PRED * 64)           // 640 threads
#define NBLK_PER_K (N_PRED / G_PRED)   // 100 blocks per pass

// Kernel 1: block = (pass k, group of G_PRED preds). Stage pass k's boxes in
// LDS once; each wave does a FULL (branchless) scan over M with min-index
// reduction -> no serial load->ballot->break latency chain. Writes per-(k,n)
// partials {u*matched, matched} to ws.
__global__ __launch_bounds__(BLK_T)
void ue_pass_kernel(const float* __restrict__ pred,    // [N,6]
                    const float* __restrict__ dpreds,  // [K,M,6]
                    const float* __restrict__ dconfs,  // [K,M,C]
                    float2* __restrict__ ws)           // [K,N]
{
    __shared__ float4 s_box[M_BOX];    // 32 KB

    const int bk   = blockIdx.x;
    const int k    = bk / NBLK_PER_K;
    const int g    = bk % NBLK_PER_K;
    const int wave = threadIdx.x >> 6;
    const int lane = threadIdx.x & 63;
    const int n    = g * G_PRED + wave;

    // cooperative stage: 2000 boxes (x1,y1,x2,y2) for pass k
    const float2* dp2 = (const float2*)dpreds;  // row = 3 float2, 8B aligned
    const long kbase = (long)k * M_BOX;
    for (int i = threadIdx.x; i < M_BOX; i += BLK_T) {
        const float2 a = dp2[(kbase + i) * 3];
        const float2 b = dp2[(kbase + i) * 3 + 1];
        s_box[i] = make_float4(a.x, a.y, b.x, b.y);
    }
    __syncthreads();

    // pred box n (wave-uniform broadcast load)
    const float px1 = pred[n * 6 + 0];
    const float py1 = pred[n * 6 + 1];
    const float px2 = pred[n * 6 + 2];
    const float py2 = pred[n * 6 + 3];
    const float area1 = (px2 - px1) * (py2 - py1);

    // branchless full scan, per-lane min of matching index
    int firstIdx = 0x7fffffff;
    #pragma unroll 4
    for (int c0 = 0; c0 < M_BOX; c0 += 64) {
        const int m = c0 + lane;
        const float4 bx = s_box[m < M_BOX ? m : (M_BOX - 1)];
        const float ix1 = fmaxf(px1, bx.x);
        const float iy1 = fmaxf(py1, bx.y);
        const float ix2 = fminf(px2, bx.z);
        const float iy2 = fminf(py2, bx.w);
        const float inter = fmaxf(ix2 - ix1, 0.0f) * fmaxf(iy2 - iy1, 0.0f);
        const float area2 = (bx.z - bx.x) * (bx.w - bx.y);
        const float iou = inter / (area1 + area2 - inter + EPS_IOU);
        if (iou > IOU_THR && m < M_BOX) firstIdx = min(firstIdx, m);
    }
    #pragma unroll
    for (int off = 32; off > 0; off >>= 1)
        firstIdx = min(firstIdx, __shfl_xor(firstIdx, off, 64));

    float um = 0.0f, mt = 0.0f;
    if (firstIdx != 0x7fffffff) {
        mt = 1.0f;
        const float* row = dconfs + (kbase + firstIdx) * (long)C_CLS;
        float local = 0.0f;
        {
            const float p = row[lane];
            local -= p * logf(p);
        }
        if (lane < C_CLS - 64) {
            const float q = row[64 + lane];
            local -= q * logf(q);
        }
        #pragma unroll
        for (int off = 32; off > 0; off >>= 1)
            local += __shfl_xor(local, off, 64);
        const float inv_n  = 1.0f / (float)C_CLS;
        const float max_en = -(float)C_CLS * (inv_n * logf(inv_n));  // log(C)
        um = 1.0f - local / max_en;
    }

    if (lane == 0) ws[(long)k * N_PRED + n] = make_float2(um, mt);
}

// Kernel 2: reduce over K passes per pred.
__global__ __launch_bounds__(256)
void ue_reduce_kernel(const float2* __restrict__ ws, float* __restrict__ out)
{
    const int n = blockIdx.x * blockDim.x + threadIdx.x;
    if (n >= N_PRED) return;
    float cnt = 0.0f, su = 0.0f;
    #pragma unroll
    for (int k = 0; k < K_PASS; ++k) {
        const float2 v = ws[(long)k * N_PRED + n];
        su  += v.x;
        cnt += v.y;
    }
    out[n] = (cnt > 0.0f) ? (su / fmaxf(cnt, 1.0f)) : __builtin_nanf("");
}

extern "C" void kernel_launch(void* const* d_in, const int* in_sizes, int n_in,
                              void* d_out, int out_size, void* d_ws, size_t ws_size,
                              hipStream_t stream) {
    const float* pred   = (const float*)d_in[0];   // [N,6]
    const float* dpreds = (const float*)d_in[1];   // [K,M,6]
    const float* dconfs = (const float*)d_in[2];   // [K,M,C]
    float* out  = (float*)d_out;                   // [N]
    float2* ws  = (float2*)d_ws;                   // [K,N] partials (80 KB)

    ue_pass_kernel<<<dim3(K_PASS * NBLK_PER_K), dim3(BLK_T), 0, stream>>>(
        pred, dpreds, dconfs, ws);
    ue_reduce_kernel<<<dim3((N_PRED + 255) / 256), dim3(256), 0, stream>>>(ws, out);
}

// Round 3
// 82.110 us; speedup vs baseline: 1.0249x; 1.0249x over previous
//
#include <hip/hip_runtime.h>
#include <math.h>

// Problem constants (from reference)
#define N_PRED 1000
#define M_BOX  2000
#define K_PASS 10
#define C_CLS  80
#define IOU_THR 0.5f
#define EPS_IOU 1e-7f

#define P_PRED 2                       // preds per wave (amortize box reads)
#define BLK_T  (K_PASS * 64)           // 640 threads: wave w == pass k
#define N_BLK  (N_PRED / P_PRED)       // 500 blocks

// Single kernel: block = (group of P_PRED preds) x all K passes.
// Wave k scans pass k's 2000 boxes (global, L2-resident) branchlessly with a
// min-index reduction (== first-match semantics), computes entropy of the
// matched class row, then a tiny in-block LDS reduction over K writes out[n].
// No workspace, no second launch, no big LDS tile.
__global__ __launch_bounds__(BLK_T)
void ue_cls_kernel(const float* __restrict__ pred,    // [N,6]
                   const float* __restrict__ dpreds,  // [K,M,6]
                   const float* __restrict__ dconfs,  // [K,M,C]
                   float* __restrict__ out)           // [N]
{
    const int k    = threadIdx.x >> 6;
    const int lane = threadIdx.x & 63;
    const int n0   = blockIdx.x * P_PRED;

    __shared__ float s_u[K_PASS][P_PRED];
    __shared__ float s_m[K_PASS][P_PRED];

    // pred boxes (wave-uniform broadcast loads)
    float px1[P_PRED], py1[P_PRED], px2[P_PRED], py2[P_PRED], a1[P_PRED];
    #pragma unroll
    for (int p = 0; p < P_PRED; ++p) {
        const float* pr = pred + (n0 + p) * 6;
        px1[p] = pr[0]; py1[p] = pr[1]; px2[p] = pr[2]; py2[p] = pr[3];
        a1[p] = (px2[p] - px1[p]) * (py2[p] - py1[p]);
    }

    // branchless full scan over pass k's boxes; per-lane min matching index
    const long kbase = (long)k * M_BOX;
    const float2* dp2 = (const float2*)dpreds;  // row = 3 float2, 8B aligned
    int firstI[P_PRED];
    #pragma unroll
    for (int p = 0; p < P_PRED; ++p) firstI[p] = 0x7fffffff;

    #pragma unroll 4
    for (int c0 = 0; c0 < M_BOX; c0 += 64) {
        const int m = c0 + lane;
        const bool valid = (m < M_BOX);
        const long i2 = (kbase + (valid ? m : M_BOX - 1)) * 3;
        const float2 a = dp2[i2];
        const float2 b = dp2[i2 + 1];
        const float area2 = (b.x - a.x) * (b.y - a.y);
        #pragma unroll
        for (int p = 0; p < P_PRED; ++p) {
            const float ix1 = fmaxf(px1[p], a.x);
            const float iy1 = fmaxf(py1[p], a.y);
            const float ix2 = fminf(px2[p], b.x);
            const float iy2 = fminf(py2[p], b.y);
            const float inter = fmaxf(ix2 - ix1, 0.0f) * fmaxf(iy2 - iy1, 0.0f);
            const float iou = inter / (a1[p] + area2 - inter + EPS_IOU);
            if (valid && iou > IOU_THR) firstI[p] = min(firstI[p], m);
        }
    }
    #pragma unroll
    for (int off = 32; off > 0; off >>= 1) {
        #pragma unroll
        for (int p = 0; p < P_PRED; ++p)
            firstI[p] = min(firstI[p], __shfl_xor(firstI[p], off, 64));
    }

    // entropy of the matched class-conf row per pred
    const float inv_n  = 1.0f / (float)C_CLS;
    const float max_en = -(float)C_CLS * (inv_n * logf(inv_n));  // == log(C)
    float um[P_PRED], mt[P_PRED];
    #pragma unroll
    for (int p = 0; p < P_PRED; ++p) {
        um[p] = 0.0f; mt[p] = 0.0f;
        if (firstI[p] != 0x7fffffff) {          // wave-uniform branch
            mt[p] = 1.0f;
            const float* row = dconfs + (kbase + firstI[p]) * (long)C_CLS;
            float local = 0.0f;
            {
                const float v = row[lane];
                local -= v * logf(v);
            }
            if (lane < C_CLS - 64) {
                const float v = row[64 + lane];
                local -= v * logf(v);
            }
            #pragma unroll
            for (int off = 32; off > 0; off >>= 1)
                local += __shfl_xor(local, off, 64);
            um[p] = 1.0f - local / max_en;
        }
    }

    if (lane == 0) {
        #pragma unroll
        for (int p = 0; p < P_PRED; ++p) {
            s_u[k][p] = um[p] * mt[p];
            s_m[k][p] = mt[p];
        }
    }
    __syncthreads();

    if (threadIdx.x < P_PRED) {
        const int t = threadIdx.x;
        float cnt = 0.0f, su = 0.0f;
        #pragma unroll
        for (int kk = 0; kk < K_PASS; ++kk) { su += s_u[kk][t]; cnt += s_m[kk][t]; }
        out[n0 + t] = (cnt > 0.0f) ? (su / fmaxf(cnt, 1.0f)) : __builtin_nanf("");
    }
}

extern "C" void kernel_launch(void* const* d_in, const int* in_sizes, int n_in,
                              void* d_out, int out_size, void* d_ws, size_t ws_size,
                              hipStream_t stream) {
    const float* pred   = (const float*)d_in[0];   // [N,6]
    const float* dpreds = (const float*)d_in[1];   // [K,M,6]
    const float* dconfs = (const float*)d_in[2];   // [K,M,C]
    float* out = (float*)d_out;                    // [N]

    ue_cls_kernel<<<dim3(N_BLK), dim3(BLK_T), 0, stream>>>(pred, dpreds, dconfs, out);
}

// Round 4
// 70.930 us; speedup vs baseline: 1.1864x; 1.1576x over previous
//
#include <hip/hip_runtime.h>
#include <math.h>

// Problem constants (from reference)
#define N_PRED 1000
#define M_BOX  2000
#define K_PASS 10
#define C_CLS  80
#define IOU_THR 0.5f
#define EPS_IOU 1e-7f

#define P_PRED 4                       // preds per wave (amortize box reads)
#define BLK_T  (K_PASS * 64)           // 640 threads: wave w == pass k
#define N_BLK  (N_PRED / P_PRED)       // 250 blocks

#define IDX_INF 0x7fffffff

// Single kernel: block = (group of P_PRED preds) x all K passes, wave k owns
// pass k. Key idea: the jittered copy of pred n sits at box index n, so the
// first match is <= n (w.h.p.) -- scan only [0, roundup(nmax+1,64)) boxes
// branchlessly (<=1024, avg ~560), min-index reduce == first-match semantics.
// A rare wave-uniform fallback loop over the remaining boxes preserves EXACT
// semantics if some pred had no match in the bounded range.
// IoU>0.5 test is divide-free: inter > 0.5*den, den in ref rounding order.
__global__ __launch_bounds__(BLK_T)
void ue_cls_kernel(const float* __restrict__ pred,    // [N,6]
                   const float* __restrict__ dpreds,  // [K,M,6]
                   const float* __restrict__ dconfs,  // [K,M,C]
                   float* __restrict__ out)           // [N]
{
    const int k    = threadIdx.x >> 6;
    const int lane = threadIdx.x & 63;
    const int n0   = blockIdx.x * P_PRED;

    __shared__ float s_u[K_PASS][P_PRED];
    __shared__ float s_m[K_PASS][P_PRED];

    // pred boxes (wave-uniform broadcast loads -> s_load)
    float px1[P_PRED], py1[P_PRED], px2[P_PRED], py2[P_PRED], a1[P_PRED];
    #pragma unroll
    for (int p = 0; p < P_PRED; ++p) {
        const float* pr = pred + (n0 + p) * 6;
        px1[p] = pr[0]; py1[p] = pr[1]; px2[p] = pr[2]; py2[p] = pr[3];
        a1[p] = (px2[p] - px1[p]) * (py2[p] - py1[p]);
    }

    const long kbase = (long)k * M_BOX;
    const float2* dp2 = (const float2*)dpreds;  // row = 3 float2, 8B aligned

    int firstI[P_PRED];
    #pragma unroll
    for (int p = 0; p < P_PRED; ++p) firstI[p] = IDX_INF;

    // bounded branchless scan: L = roundup(nmax+1, 64) <= 1024 < M, so no
    // bounds checks needed in this loop.
    const int L = (((n0 + P_PRED - 1) >> 6) << 6) + 64;
    for (int c0 = 0; c0 < L; c0 += 64) {
        const int m = c0 + lane;
        const long i2 = (kbase + m) * 3;
        const float2 a = dp2[i2];
        const float2 b = dp2[i2 + 1];
        const float area2 = (b.x - a.x) * (b.y - a.y);
        #pragma unroll
        for (int p = 0; p < P_PRED; ++p) {
            const float ix1 = fmaxf(px1[p], a.x);
            const float iy1 = fmaxf(py1[p], a.y);
            const float ix2 = fminf(px2[p], b.x);
            const float iy2 = fminf(py2[p], b.y);
            const float inter = fmaxf(ix2 - ix1, 0.0f) * fmaxf(iy2 - iy1, 0.0f);
            const float den = a1[p] + area2 - inter + EPS_IOU;  // ref rounding order
            if (inter > 0.5f * den) firstI[p] = min(firstI[p], m);
        }
    }
    #pragma unroll
    for (int off = 32; off > 0; off >>= 1) {
        #pragma unroll
        for (int p = 0; p < P_PRED; ++p)
            firstI[p] = min(firstI[p], __shfl_xor(firstI[p], off, 64));
    }

    // exactness fallback: if any pred unmatched in [0,L), scan the rest.
    bool need = false;
    #pragma unroll
    for (int p = 0; p < P_PRED; ++p) need = need || (firstI[p] == IDX_INF);
    if (need) {  // wave-uniform, rare
        for (int c0 = L; c0 < M_BOX; c0 += 64) {
            const int m = c0 + lane;
            const bool valid = (m < M_BOX);
            const long i2 = (kbase + (valid ? m : M_BOX - 1)) * 3;
            const float2 a = dp2[i2];
            const float2 b = dp2[i2 + 1];
            const float area2 = (b.x - a.x) * (b.y - a.y);
            #pragma unroll
            for (int p = 0; p < P_PRED; ++p) {
                const float ix1 = fmaxf(px1[p], a.x);
                const float iy1 = fmaxf(py1[p], a.y);
                const float ix2 = fminf(px2[p], b.x);
                const float iy2 = fminf(py2[p], b.y);
                const float inter = fmaxf(ix2 - ix1, 0.0f) * fmaxf(iy2 - iy1, 0.0f);
                const float den = a1[p] + area2 - inter + EPS_IOU;
                if (valid && inter > 0.5f * den) firstI[p] = min(firstI[p], m);
            }
        }
        #pragma unroll
        for (int off = 32; off > 0; off >>= 1) {
            #pragma unroll
            for (int p = 0; p < P_PRED; ++p)
                firstI[p] = min(firstI[p], __shfl_xor(firstI[p], off, 64));
        }
    }

    // entropy of the matched class-conf row per pred (identical math to ref)
    const float inv_n  = 1.0f / (float)C_CLS;
    const float max_en = -(float)C_CLS * (inv_n * logf(inv_n));  // == log(C)
    float um[P_PRED], mt[P_PRED];
    #pragma unroll
    for (int p = 0; p < P_PRED; ++p) {
        um[p] = 0.0f; mt[p] = 0.0f;
        if (firstI[p] != IDX_INF) {  // wave-uniform branch
            mt[p] = 1.0f;
            const float* row = dconfs + (kbase + firstI[p]) * (long)C_CLS;
            float local = 0.0f;
            {
                const float v = row[lane];
                local -= v * logf(v);
            }
            if (lane < C_CLS - 64) {
                const float v = row[64 + lane];
                local -= v * logf(v);
            }
            #pragma unroll
            for (int off = 32; off > 0; off >>= 1)
                local += __shfl_xor(local, off, 64);
            um[p] = 1.0f - local / max_en;
        }
    }

    if (lane == 0) {
        #pragma unroll
        for (int p = 0; p < P_PRED; ++p) {
            s_u[k][p] = um[p] * mt[p];
            s_m[k][p] = mt[p];
        }
    }
    __syncthreads();

    if (threadIdx.x < P_PRED) {
        const int t = threadIdx.x;
        float cnt = 0.0f, su = 0.0f;
        #pragma unroll
        for (int kk = 0; kk < K_PASS; ++kk) { su += s_u[kk][t]; cnt += s_m[kk][t]; }
        out[n0 + t] = (cnt > 0.0f) ? (su / fmaxf(cnt, 1.0f)) : __builtin_nanf("");
    }
}

extern "C" void kernel_launch(void* const* d_in, const int* in_sizes, int n_in,
                              void* d_out, int out_size, void* d_ws, size_t ws_size,
                              hipStream_t stream) {
    const float* pred   = (const float*)d_in[0];   // [N,6]
    const float* dpreds = (const float*)d_in[1];   // [K,M,6]
    const float* dconfs = (const float*)d_in[2];   // [K,M,C]
    float* out = (float*)d_out;                    // [N]

    ue_cls_kernel<<<dim3(N_BLK), dim3(BLK_T), 0, stream>>>(pred, dpreds, dconfs, out);
}